// Round 8
// baseline (231.482 us; speedup 1.0000x reference)
//
#include <hip/hip_runtime.h>

typedef short short8 __attribute__((ext_vector_type(8)));
typedef float f32x4 __attribute__((ext_vector_type(4)));

#define H_ 384
#define W_ 384
#define C_ 32
#define F_ 32
#define HW_ 147456          // H_*W_
#define HP1F 385.0f         // (H+2*pad)-1 as float
#define NB 2                // pixel batches per wave

__device__ __forceinline__ unsigned short f2bf(float f) {
  unsigned int u = __float_as_uint(f);
  u += 0x7fffu + ((u >> 16) & 1u);   // RNE
  return (unsigned short)(u >> 16);
}

__global__ __launch_bounds__(256) void deform_conv_kernel(
    const float* __restrict__ x, const float* __restrict__ off,
    const float* __restrict__ kern, const float* __restrict__ bias,
    float* __restrict__ out) {
  // LDS (18.4 KB): B-fragment STAGING only (dead after the two barriers).
  // B lives in registers in the main loop — exactly R5's passing B path.
  // A-fragments are gathered directly into registers (R6 structure): lane L
  // owns pixel L&15, channels (L>>4)*8..+7 == MFMA A-operand layout, so the
  // main loop has ZERO LDS traffic and gathers pipeline freely across taps.
  __shared__ short ldsB[9216];

  const int tid = threadIdx.x;
  const int lane = tid & 63;
  const int wv = tid >> 6;

  // ---- stage packed B fragments (bf16, MFMA B-operand layout) through LDS
  // ---- into REGISTERS (verbatim R5 path: two barriers, reg-resident bfrag).
  short8 bfrag[2][9];
  {
    unsigned short* pk = (unsigned short*)ldsB;
    for (int e = tid; e < 1152; e += 256) {   // 2 f-tiles * 9 k-steps * 64 lanes
      const int ln = e & 63;
      const int kk = (e >> 6) % 9;
      const int nt = e / 576;
      const int f = nt * 16 + (ln & 15);
      const int q2 = ln >> 4;
      unsigned short rr[8];
#pragma unroll
      for (int i2 = 0; i2 < 8; ++i2) {
        const int c = q2 * 8 + i2;                     // contraction idx = kk*32 + c
        rr[i2] = f2bf(kern[(kk * 32 + c) * 32 + f]);
      }
      uint4 w;
      w.x = rr[0] | ((unsigned)rr[1] << 16);
      w.y = rr[2] | ((unsigned)rr[3] << 16);
      w.z = rr[4] | ((unsigned)rr[5] << 16);
      w.w = rr[6] | ((unsigned)rr[7] << 16);
      *(uint4*)&pk[e * 8] = w;
    }
    __syncthreads();
    const short8* bp = (const short8*)ldsB;
#pragma unroll
    for (int nt = 0; nt < 2; ++nt)
#pragma unroll
      for (int kk = 0; kk < 9; ++kk)
        bfrag[nt][kk] = bp[(nt * 9 + kk) * 64 + lane];
    __syncthreads();
  }

  const float bias0 = bias[lane & 15];
  const float bias1 = bias[16 + (lane & 15)];

  const int px = lane & 15;         // pixel within 16-tile == MFMA A row
  const int qq = lane >> 4;         // MFMA quad; channels qq*8..qq*8+7
  const int cb = qq * 8;            // first channel this lane owns

  // XCD-aware swizzle: physical block p lands on XCD p%8; give each XCD a
  // contiguous run of 288 logical blocks (96 contiguous image rows) so its
  // 4 MiB L2 holds the streaming reuse window and the halo is fetched by
  // exactly one XCD. Bijection over [0,2304): blk=8q+r -> 288r+q.
  const int lb = (blockIdx.x & 7) * 288 + (blockIdx.x >> 3);

  for (int nb = 0; nb < NB; ++nb) {
    const int g = lb * (4 * NB) + nb * 4 + wv;           // wave-group index
    const int P0 = g << 4;                               // first of 16 pixels
    const int b = (P0 >= HW_) ? 1 : 0;
    const int rem = P0 - b * HW_;
    const int i = rem / W_;
    const int j0 = rem - i * W_;     // group never crosses a row (W%16==0)
    const int j = j0 + px;

    f32x4 acc0 = {bias0, bias0, bias0, bias0};
    f32x4 acc1 = {bias1, bias1, bias1, bias1};

    // ---- per-tap: gather own A-fragment (8 ch, 4 corners), MFMA ----
#pragma unroll
    for (int kk = 0; kk < 9; ++kk) {
      const int di = kk / 3;
      const int dj = kk - di * 3;
      const float2 o = *(const float2*)(off + (((i * W_) + j) * 9 + kk) * 2);
      float yf = (float)(i + di) + o.y;   // padded coords; o.y = y_off
      float xf = (float)(j + dj) + o.x;   // o.x = x_off
      yf = fminf(fmaxf(yf, 0.f), HP1F);
      xf = fminf(fmaxf(xf, 0.f), HP1F);
      const float y0f = floorf(yf);
      const float x0f = floorf(xf);
      const int y0 = (int)y0f;
      const int x0 = (int)x0f;

      float v[8];
      // Fast path: all 4 corners strictly inside the image; wave-uniform
      // branch via __all (~94% of iterations, offsets ~N(0,1)).
      const int fast = ((unsigned)(y0 - 1) < 383u) & ((unsigned)(x0 - 1) < 383u);
      if (__all(fast)) {
        const float wy1 = yf - y0f;
        const float wy0 = (y0f + 1.0f) - yf;   // == (float)y1 - yf, y1=y0+1
        const float wx1 = xf - x0f;
        const float wx0 = (x0f + 1.0f) - xf;
        const float w00 = wy0 * wx0, w01 = wy0 * wx1;
        const float w10 = wy1 * wx0, w11 = wy1 * wx1;
        const int base00 = ((b * H_ + (y0 - 1)) * W_ + (x0 - 1)) * C_ + cb;
        // 8 unconditional, independent 16B loads -> all in flight together
        const float4 p00a = *(const float4*)(x + base00);
        const float4 p00b = *(const float4*)(x + base00 + 4);
        const float4 p01a = *(const float4*)(x + base00 + C_);
        const float4 p01b = *(const float4*)(x + base00 + C_ + 4);
        const float4 p10a = *(const float4*)(x + base00 + W_ * C_);
        const float4 p10b = *(const float4*)(x + base00 + W_ * C_ + 4);
        const float4 p11a = *(const float4*)(x + base00 + W_ * C_ + C_);
        const float4 p11b = *(const float4*)(x + base00 + W_ * C_ + C_ + 4);
        v[0] = w00 * p00a.x + w01 * p01a.x + w10 * p10a.x + w11 * p11a.x;
        v[1] = w00 * p00a.y + w01 * p01a.y + w10 * p10a.y + w11 * p11a.y;
        v[2] = w00 * p00a.z + w01 * p01a.z + w10 * p10a.z + w11 * p11a.z;
        v[3] = w00 * p00a.w + w01 * p01a.w + w10 * p10a.w + w11 * p11a.w;
        v[4] = w00 * p00b.x + w01 * p01b.x + w10 * p10b.x + w11 * p11b.x;
        v[5] = w00 * p00b.y + w01 * p01b.y + w10 * p10b.y + w11 * p11b.y;
        v[6] = w00 * p00b.z + w01 * p01b.z + w10 * p10b.z + w11 * p11b.z;
        v[7] = w00 * p00b.w + w01 * p01b.w + w10 * p10b.w + w11 * p11b.w;
      } else {
        // Slow path: R0-style guarded loads (pad corners -> 0), 8 channels.
        const int y1 = min(y0 + 1, 385);
        const int x1 = min(x0 + 1, 385);
        const float wy1 = yf - y0f;
        const float wy0 = (float)y1 - yf;
        const float wx1 = xf - x0f;
        const float wx0 = (float)x1 - xf;
        const float w00 = wy0 * wx0, w01 = wy0 * wx1;
        const float w10 = wy1 * wx0, w11 = wy1 * wx1;

        const int yu0 = y0 - 1, xu0 = x0 - 1;
        const bool vy0 = (unsigned)yu0 < 384u, vy1 = (unsigned)(y1 - 1) < 384u;
        const bool vx0 = (unsigned)xu0 < 384u, vx1 = (unsigned)(x1 - 1) < 384u;
        const int base00 = ((b * H_ + yu0) * W_ + xu0) * C_ + cb;
        const int ddx = (x1 - x0) * C_;
        const int ddy = (y1 - y0) * (W_ * C_);
        float4 p00a = {0,0,0,0}, p00b = {0,0,0,0}, p01a = {0,0,0,0}, p01b = {0,0,0,0};
        float4 p10a = {0,0,0,0}, p10b = {0,0,0,0}, p11a = {0,0,0,0}, p11b = {0,0,0,0};
        if (vy0 && vx0) { p00a = *(const float4*)(x + base00);
                          p00b = *(const float4*)(x + base00 + 4); }
        if (vy0 && vx1) { p01a = *(const float4*)(x + base00 + ddx);
                          p01b = *(const float4*)(x + base00 + ddx + 4); }
        if (vy1 && vx0) { p10a = *(const float4*)(x + base00 + ddy);
                          p10b = *(const float4*)(x + base00 + ddy + 4); }
        if (vy1 && vx1) { p11a = *(const float4*)(x + base00 + ddy + ddx);
                          p11b = *(const float4*)(x + base00 + ddy + ddx + 4); }
        v[0] = w00 * p00a.x + w01 * p01a.x + w10 * p10a.x + w11 * p11a.x;
        v[1] = w00 * p00a.y + w01 * p01a.y + w10 * p10a.y + w11 * p11a.y;
        v[2] = w00 * p00a.z + w01 * p01a.z + w10 * p10a.z + w11 * p11a.z;
        v[3] = w00 * p00a.w + w01 * p01a.w + w10 * p10a.w + w11 * p11a.w;
        v[4] = w00 * p00b.x + w01 * p01b.x + w10 * p10b.x + w11 * p11b.x;
        v[5] = w00 * p00b.y + w01 * p01b.y + w10 * p10b.y + w11 * p11b.y;
        v[6] = w00 * p00b.z + w01 * p01b.z + w10 * p10b.z + w11 * p11b.z;
        v[7] = w00 * p00b.w + w01 * p01b.w + w10 * p10b.w + w11 * p11b.w;
      }

      // pack A-fragment: element j == contraction index cb+j  (A[m][k] layout)
      uint4 aw;
      aw.x = f2bf(v[0]) | ((unsigned)f2bf(v[1]) << 16);
      aw.y = f2bf(v[2]) | ((unsigned)f2bf(v[3]) << 16);
      aw.z = f2bf(v[4]) | ((unsigned)f2bf(v[5]) << 16);
      aw.w = f2bf(v[6]) | ((unsigned)f2bf(v[7]) << 16);
      const short8 af = __builtin_bit_cast(short8, aw);

      acc0 = __builtin_amdgcn_mfma_f32_16x16x32_bf16(af, bfrag[0][kk], acc0, 0, 0, 0);
      acc1 = __builtin_amdgcn_mfma_f32_16x16x32_bf16(af, bfrag[1][kk], acc1, 0, 0, 0);
    }

    // D layout: col = lane&15, row = qq*4 + reg
    float* op = out + (size_t)(P0 + qq * 4) * 32 + (lane & 15);
#pragma unroll
    for (int r = 0; r < 4; ++r) {
      op[r * 32] = acc0[r];
      op[r * 32 + 16] = acc1[r];
    }
  }
}

extern "C" void kernel_launch(void* const* d_in, const int* in_sizes, int n_in,
                              void* d_out, int out_size, void* d_ws, size_t ws_size,
                              hipStream_t stream) {
  const float* x    = (const float*)d_in[0];
  const float* off  = (const float*)d_in[1];
  const float* kern = (const float*)d_in[2];
  const float* bias = (const float*)d_in[3];
  float* out = (float*)d_out;
  // 294912 pixels / (4 waves * 16 px * NB batches) = 2304 blocks
  deform_conv_kernel<<<dim3(2304), dim3(256), 0, stream>>>(x, off, kern, bias, out);
}